// Round 1
// 506.839 us; speedup vs baseline: 1.2139x; 1.2139x over previous
//
#include <hip/hip_runtime.h>
#include <math.h>

#define HH 128
#define WW 128
#define CG 8
#define NN 256
#define HWSZ (HH*WW)

typedef __bf16 bf16x8 __attribute__((ext_vector_type(8)));
typedef short short8v __attribute__((ext_vector_type(8)));
typedef float f32x4 __attribute__((ext_vector_type(4)));

__device__ __forceinline__ float sigmoidf_(float x){ return 1.0f/(1.0f+__expf(-x)); }

__device__ __forceinline__ unsigned short f2bf(float x){
  union { float f; unsigned u; } v; v.f = x;
  unsigned r = v.u + 0x7fffu + ((v.u >> 16) & 1u);
  return (unsigned short)(r >> 16);
}
__device__ __forceinline__ float bf2f(unsigned short h){
  union { unsigned u; float f; } v; v.u = ((unsigned)h) << 16; return v.f;
}

// ---------------- Kernel W: pre-scale 5x5 weights by softmax(scale_w)[2] -------
__global__ void kW(const float* __restrict__ w5, const float* __restrict__ scw,
                   float* __restrict__ w5s){
  int i = blockIdx.x*256 + threadIdx.x;
  if (i >= CG*CG*25) return;
  float a = scw[0], b = scw[1], c = scw[2];
  float m = fmaxf(a, fmaxf(b, c));
  float e0 = __expf(a-m), e1 = __expf(b-m), e2 = __expf(c-m);
  float sw2 = e2 / (e0+e1+e2);
  w5s[i] = sw2 * w5[i];
}

// ---------------- Kernel A1: per-(n,c) row & column means ----------------------
__global__ __launch_bounds__(256) void kA1(const float* __restrict__ gx,
                                           float* __restrict__ xh_ws,
                                           float* __restrict__ xw_ws){
  int b = blockIdx.x; int n = b >> 3; int c = b & 7;
  int tid = threadIdx.x;
  __shared__ float colpart[2][WW];
  const float* img = gx + (size_t)(n*CG+c)*HWSZ;
  // column sums (coalesced HBM read)
  int w = tid & 127, half = tid >> 7;
  float acc = 0.f;
  const float* p = img + half*64*WW + w;
  for (int h = 0; h < 64; ++h) acc += p[h*WW];
  colpart[half][w] = acc;
  // row sums (L2-hot second read)
  int h2 = tid >> 1, wh = tid & 1;
  float racc = 0.f;
  const float* rp = img + h2*WW + wh*64;
  for (int j = 0; j < 64; ++j) racc += rp[j];
  racc += __shfl_xor(racc, 1);
  __syncthreads();
  if (tid < WW) xw_ws[(n*CG+c)*WW + tid] = (colpart[0][tid] + colpart[1][tid]) * (1.0f/HH);
  if (wh == 0) xh_ws[(n*CG+c)*HH + h2] = racc * (1.0f/WW);
}

// ---------------- Kernel A2: 8x8 fuse conv + sigmoid ---------------------------
__global__ __launch_bounds__(256) void kA2(const float* __restrict__ xh_ws,
                                           const float* __restrict__ xw_ws,
                                           const float* __restrict__ afw,
                                           float* __restrict__ sig_h,
                                           float* __restrict__ sig_w){
  int n = blockIdx.x;
  int tid = threadIdx.x;
  if (tid < HH){
    int h = tid;
    float v[CG];
    #pragma unroll
    for (int c = 0; c < CG; ++c) v[c] = xh_ws[(n*CG+c)*HH + h];
    #pragma unroll
    for (int o = 0; o < CG; ++o){
      float s = 0.f;
      #pragma unroll
      for (int i = 0; i < CG; ++i) s = fmaf(afw[o*CG+i], v[i], s);
      sig_h[(n*CG+o)*HH + h] = sigmoidf_(s);
    }
  } else {
    int w = tid - 128;
    float v[CG];
    #pragma unroll
    for (int c = 0; c < CG; ++c) v[c] = xw_ws[(n*CG+c)*WW + w];
    #pragma unroll
    for (int o = 0; o < CG; ++o){
      float s = 0.f;
      #pragma unroll
      for (int i = 0; i < CG; ++i) s = fmaf(afw[o*CG+i], v[i], s);
      sig_w[(n*CG+o)*WW + w] = sigmoidf_(s);
    }
  }
}

// ---------------- Kernel B: GroupNorm stats of t = gx*sigh*sigw ----------------
__global__ __launch_bounds__(256) void kB(const float* __restrict__ gx,
                                          const float* __restrict__ sig_h,
                                          const float* __restrict__ sig_w,
                                          const float* __restrict__ gn_w,
                                          const float* __restrict__ gn_b,
                                          float* __restrict__ Agn,
                                          float* __restrict__ Bgn){
  int b = blockIdx.x; int n = b >> 3; int c = b & 7;
  int tid = threadIdx.x;
  __shared__ float sh[HH];
  __shared__ float swv[WW];
  __shared__ float red[16];
  if (tid < HH) sh[tid] = sig_h[(n*CG+c)*HH + tid];
  else          swv[tid-128] = sig_w[(n*CG+c)*WW + tid - 128];
  __syncthreads();
  const float* img = gx + (size_t)(n*CG+c)*HWSZ;
  float s1 = 0.f, s2 = 0.f;
  for (int idx = tid; idx < HWSZ; idx += 256){
    int h = idx >> 7, w = idx & 127;
    float t = img[idx] * sh[h] * swv[w];
    s1 += t; s2 = fmaf(t, t, s2);
  }
  #pragma unroll
  for (int off = 32; off; off >>= 1){ s1 += __shfl_down(s1, off); s2 += __shfl_down(s2, off); }
  int wv = tid >> 6, ln = tid & 63;
  if (ln == 0){ red[wv] = s1; red[8+wv] = s2; }
  __syncthreads();
  if (tid == 0){
    float S1 = red[0]+red[1]+red[2]+red[3];
    float S2 = red[8]+red[9]+red[10]+red[11];
    float mu  = S1 * (1.0f/HWSZ);
    float var = S2 * (1.0f/HWSZ) - mu*mu;
    float rstd = rsqrtf(var + 1e-5f);
    float A = rstd * gn_w[c];
    Agn[n*CG+c] = A;
    Bgn[n*CG+c] = gn_b[c] - mu*A;
  }
}

// ---------------- Kernel C: MFMA implicit-GEMM fused convs ---------------------
// GEMM view: M = pixels (16-wide half-rows of a 32x32 tile), N = 16
// (cols 0..7 = x1 conv path (sw2*5x5 + gated 1x1), cols 8..15 = raw 3x3 = x2),
// K = 4 taps x 8 ic per k-step, 7 steps (25 conv5 taps + gated tap + 2 dummies).
// LDS tile layout [y][x][ic] bf16 -> A-fragment = one ds_read_b128 per lane.
// Weights split bf16 hi+lo for cols 0..7 (keeps fp32-weight accuracy); conv3
// hi-only (x2's bf16 storage rounding dominates). Activations bf16 as before.
__global__ __launch_bounds__(256) void kC(const float* __restrict__ gx,
                                          const float* __restrict__ w1,
                                          const float* __restrict__ w3,
                                          const float* __restrict__ w5s,
                                          const float* __restrict__ scale_w,
                                          const float* __restrict__ spw,
                                          const float* __restrict__ sig_h,
                                          const float* __restrict__ sig_w,
                                          const float* __restrict__ Agn,
                                          const float* __restrict__ Bgn,
                                          unsigned short* __restrict__ x1m,
                                          unsigned short* __restrict__ x2m,
                                          float* __restrict__ gacc){
  // rows 0..35: raw 36x36 haloed tile; rows 36..67: gated center (cols 2..33)
  __shared__ __align__(16) unsigned short tile[68*36*8];   // 39168 B
  __shared__ __align__(16) unsigned short Bm[7][16][32];   // 7168 B  (hi)
  __shared__ __align__(16) unsigned short BmLo[7][8][32];  // 3584 B  (lo, cols 0..7)
  __shared__ float sighs[CG][32];
  __shared__ float sigws[CG][32];
  __shared__ float constA[CG];
  __shared__ float wred[4][32];

  int tid = threadIdx.x;
  int bb = blockIdx.x;
  int n  = bb >> 4;
  int t_ = bb & 15;
  int y0 = (t_ >> 2) * 32;
  int x0 = (t_ & 3) * 32;

  float sw0, sw1;
  {
    float a = scale_w[0], b = scale_w[1], c = scale_w[2];
    float m = fmaxf(a, fmaxf(b, c));
    float e0 = __expf(a-m), e1 = __expf(b-m), e2 = __expf(c-m);
    float inv = 1.0f/(e0+e1+e2);
    sw0 = e0*inv; sw1 = e1*inv;
  }
  {
    int ic = tid >> 5, k = tid & 31;
    sighs[ic][k] = sig_h[(n*CG+ic)*HH + y0 + k];
    sigws[ic][k] = sig_w[(n*CG+ic)*WW + x0 + k];
  }
  if (tid < CG){
    float s = 0.f;
    #pragma unroll
    for (int i = 0; i < CG; ++i) s = fmaf(w1[tid*CG+i], Bgn[n*CG+i], s);
    constA[tid] = sw0 * s;
  }

  // ---- stage raw 36x36 halo tile, ic in pairs (b32 LDS writes, 2-way=free) ----
  const float* base_n = gx + (size_t)n*CG*HWSZ;
  #pragma unroll
  for (int p = 0; p < 4; ++p){
    const float* i0 = base_n + (size_t)(2*p)*HWSZ;
    const float* i1 = base_n + (size_t)(2*p+1)*HWSZ;
    for (int e = tid; e < 1296; e += 256){
      int yy = e / 36, xx = e - yy*36;
      int gy = y0 + yy - 2, gz = x0 + xx - 2;
      float v0 = 0.f, v1 = 0.f;
      if ((unsigned)gy < HH && (unsigned)gz < WW){
        int o = gy*WW + gz; v0 = i0[o]; v1 = i1[o];
      }
      unsigned pk = (unsigned)f2bf(v0) | ((unsigned)f2bf(v1) << 16);
      *reinterpret_cast<unsigned*>(&tile[(yy*36 + xx)*8 + 2*p]) = pk;
    }
  }

  // ---- build B matrices: B[k = tap_in_step*8 + ic][n] stored as [n][k] --------
  for (int e = tid; e < 3584; e += 256){
    int s   = e >> 9;        // 0..6
    int rem = e & 511;
    int nn = rem >> 5, kk = rem & 31;
    int tap = s*4 + (kk >> 3);
    int ic  = kk & 7;
    float wv = 0.f;
    if (nn < 8){
      if (tap < 25)       wv = w5s[nn*200 + ic*25 + tap];           // sw2*w5 (ky=tap/5,kx=tap%5)
      else if (tap == 25) wv = sw0 * w1[nn*CG + ic] * Agn[n*CG + ic]; // gated 1x1 coef
    } else if (tap < 25){
      int ky = tap/5, kx = tap - ky*5;
      if (ky >= 1 && ky <= 3 && kx >= 1 && kx <= 3)
        wv = w3[(nn-8)*72 + ic*9 + (ky-1)*3 + (kx-1)];
    }
    unsigned short hi = f2bf(wv);
    Bm[s][nn][kk] = hi;
    if (nn < 8) BmLo[s][nn][kk] = f2bf(wv - bf2f(hi));
  }
  __syncthreads();

  // ---- build gated center tile (t = raw*sigh*sigw), rows 36..67 cols 2..33 ----
  #pragma unroll
  for (int p = 0; p < 4; ++p){
    for (int e = tid; e < 1024; e += 256){
      int yl = e >> 5, xl = e & 31;
      unsigned pk = *reinterpret_cast<const unsigned*>(&tile[((yl+2)*36 + xl+2)*8 + 2*p]);
      float v0 = bf2f((unsigned short)(pk & 0xffffu)) * sighs[2*p][yl]   * sigws[2*p][xl];
      float v1 = bf2f((unsigned short)(pk >> 16))     * sighs[2*p+1][yl] * sigws[2*p+1][xl];
      unsigned opk = (unsigned)f2bf(v0) | ((unsigned)f2bf(v1) << 16);
      *reinterpret_cast<unsigned*>(&tile[((yl+36)*36 + xl+2)*8 + 2*p]) = opk;
    }
  }

  // ---- per-lane B fragments (kept in registers) and tap address offsets -------
  int lane = tid & 63;
  int wid  = tid >> 6;
  int pr = lane & 15;   // A-role: pixel row; B/D-role: output column n
  int tg = lane >> 4;   // k-block (tap within step); D-role: pixel quad
  short8v zs = {0,0,0,0,0,0,0,0};
  bf16x8 zb = __builtin_bit_cast(bf16x8, zs);
  bf16x8 bH[7], bL[7];
  int ofs[7];
  #pragma unroll
  for (int s = 0; s < 7; ++s){
    bH[s] = *reinterpret_cast<const bf16x8*>(&Bm[s][pr][tg*8]);
    bL[s] = (pr < 8) ? *reinterpret_cast<const bf16x8*>(&BmLo[s][pr][tg*8]) : zb;
    int t = s*4 + tg;
    int ky, kx;
    if (t < 25){ ky = t/5; kx = t - ky*5; }
    else if (t == 25){ ky = 36; kx = 2; }   // gated tile alias in same address space
    else { ky = 0; kx = 0; }                // dummy taps (B=0)
    ofs[s] = (ky*36 + kx)*8;                // ushort units
  }
  __syncthreads();

  float cA  = (pr < 8) ? constA[pr] : 0.f;
  float spv = spw[pr & 7];
  float sAcc = 0.f, qAcc = 0.f;  // lanes pr<8: (s1,qq1); pr>=8: (s2,qq2)

  #pragma unroll 2
  for (int i = 0; i < 16; ++i){
    int mb = wid*16 + i;          // wave owns rows y = wid*8 .. wid*8+7
    int yl = mb >> 1;
    int xh = (mb & 1) << 4;
    const unsigned short* abase = &tile[(yl*36 + xh + pr)*8];
    f32x4 accP = {0.f,0.f,0.f,0.f};
    f32x4 accQ = {0.f,0.f,0.f,0.f};
    #pragma unroll
    for (int s = 0; s < 7; ++s){
      bf16x8 a = *reinterpret_cast<const bf16x8*>(abase + ofs[s]);
      accP = __builtin_amdgcn_mfma_f32_16x16x32_bf16(a, bH[s], accP, 0, 0, 0);
      accQ = __builtin_amdgcn_mfma_f32_16x16x32_bf16(a, bL[s], accQ, 0, 0, 0);
    }
    // D layout: lane holds D[pixel = tg*4 + r][n = pr]
    float av[4], ot[4], vv[4], sg[4];
    #pragma unroll
    for (int r = 0; r < 4; ++r) av[r] = accP[r] + accQ[r];
    #pragma unroll
    for (int r = 0; r < 4; ++r) ot[r] = __shfl_xor(av[r], 8);   // partner column n^8
    #pragma unroll
    for (int r = 0; r < 4; ++r)
      vv[r] = (pr < 8) ? (av[r] + cA + sw1*ot[r]) : av[r];      // v1 | x2
    #pragma unroll
    for (int r = 0; r < 4; ++r){                                 // sp-gate: sum over 8 oc
      float t = spv * vv[r];
      t += __shfl_xor(t, 1);
      t += __shfl_xor(t, 2);
      t += __shfl_xor(t, 4);
      sg[r] = sigmoidf_(t);
    }
    ushort4 u;
    #pragma unroll
    for (int r = 0; r < 4; ++r){
      sAcc += vv[r];
      qAcc = fmaf(vv[r], sg[r], qAcc);
      ((unsigned short*)&u)[r] = f2bf(vv[r]);
    }
    int gy  = y0 + yl;
    int gxx = x0 + xh + tg*4;
    size_t off = ((size_t)(n*CG + (pr & 7))*HH + gy)*WW + gxx;
    if (pr < 8) *reinterpret_cast<ushort4*>(x1m + off) = u;
    else        *reinterpret_cast<ushort4*>(x2m + off) = u;
  }

  // reduce partials across the 4 pixel-quad groups (lanes differing in bits 4,5)
  sAcc += __shfl_xor(sAcc, 16); sAcc += __shfl_xor(sAcc, 32);
  qAcc += __shfl_xor(qAcc, 16); qAcc += __shfl_xor(qAcc, 32);
  if (lane < 16){
    int b0 = (pr < 8) ? pr : (8 + pr);   // -> slots {oc, 8+oc} | {16+oc, 24+oc}
    wred[wid][b0]     = sAcc;
    wred[wid][b0 + 8] = qAcc;
  }
  __syncthreads();
  if (tid < 32){
    float s = wred[0][tid] + wred[1][tid] + wred[2][tid] + wred[3][tid];
    atomicAdd(&gacc[n*32 + tid], s);
  }
}

// ---------------- Kernel T: channel gates + softmaxes -> a1,a2 -----------------
__global__ void kT(const float* __restrict__ gacc, const float* __restrict__ cgw,
                   float* __restrict__ a1a2){
  int n = blockIdx.x*blockDim.x + threadIdx.x;
  if (n >= NN) return;
  const float* g = gacc + n*32;
  float m1[CG], q1[CG], m2[CG], q2[CG];
  #pragma unroll
  for (int c = 0; c < CG; ++c){
    m1[c] = g[c]      * (1.0f/HWSZ);
    q1[c] = g[8+c]    * (1.0f/HWSZ);
    m2[c] = g[16+c]   * (1.0f/HWSZ);
    q2[c] = g[24+c]   * (1.0f/HWSZ);
  }
  float chg1[CG], chg2[CG];
  #pragma unroll
  for (int o = 0; o < CG; ++o){
    float s1 = 0.f, s2 = 0.f;
    #pragma unroll
    for (int i = 0; i < CG; ++i){ s1 = fmaf(cgw[o*CG+i], m1[i], s1); s2 = fmaf(cgw[o*CG+i], m2[i], s2); }
    chg1[o] = sigmoidf_(s1); chg2[o] = sigmoidf_(s2);
  }
  float z1[CG], z2[CG];
  float mx1 = -1e30f, mx2 = -1e30f;
  #pragma unroll
  for (int c = 0; c < CG; ++c){
    z1[c] = chg1[c]*q1[c]; z2[c] = chg2[c]*q2[c];
    mx1 = fmaxf(mx1, z1[c]); mx2 = fmaxf(mx2, z2[c]);
  }
  float su1 = 0.f, su2 = 0.f;
  #pragma unroll
  for (int c = 0; c < CG; ++c){
    z1[c] = __expf(z1[c]-mx1); su1 += z1[c];
    z2[c] = __expf(z2[c]-mx2); su2 += z2[c];
  }
  float i1 = 1.0f/su1, i2 = 1.0f/su2;
  #pragma unroll
  for (int c = 0; c < CG; ++c){
    float x11 = z1[c]*i1;
    float x21 = z2[c]*i2;
    a1a2[n*16 + c]     = x21 * chg1[c];
    a1a2[n*16 + 8 + c] = x11 * chg2[c];
  }
}

// ---------------- Kernel F: final weights + output -----------------------------
__global__ __launch_bounds__(256) void kF(const float* __restrict__ gx,
                                          const unsigned short* __restrict__ x1m,
                                          const unsigned short* __restrict__ x2m,
                                          const float* __restrict__ a1a2,
                                          const float* __restrict__ spw,
                                          float* __restrict__ out){
  int tid = threadIdx.x;
  int bb = blockIdx.x;
  int n  = bb >> 6;
  int hw = ((bb & 63) << 8) + tid;
  size_t base = (size_t)(n*CG)*HWSZ + hw;
  float a1[CG], a2[CG], sp[CG];
  #pragma unroll
  for (int c = 0; c < CG; ++c){
    a1[c] = a1a2[n*16 + c];
    a2[c] = a1a2[n*16 + 8 + c];
    sp[c] = spw[c];
  }
  float d1 = 0.f, dd1 = 0.f, d2 = 0.f, dd2 = 0.f;
  #pragma unroll
  for (int c = 0; c < CG; ++c){
    float v1 = bf2f(x1m[base + (size_t)c*HWSZ]);
    float v2 = bf2f(x2m[base + (size_t)c*HWSZ]);
    d1  = fmaf(sp[c], v1, d1);  dd1 = fmaf(a1[c], v1, dd1);
    d2  = fmaf(sp[c], v2, d2);  dd2 = fmaf(a2[c], v2, dd2);
  }
  float Wv = sigmoidf_(d1)*dd1 + sigmoidf_(d2)*dd2;
  float sW = sigmoidf_(Wv);
  #pragma unroll
  for (int c = 0; c < CG; ++c)
    out[base + (size_t)c*HWSZ] = gx[base + (size_t)c*HWSZ] * sW;
}

extern "C" void kernel_launch(void* const* d_in, const int* in_sizes, int n_in,
                              void* d_out, int out_size, void* d_ws, size_t ws_size,
                              hipStream_t stream){
  const float* x   = (const float*)d_in[0];
  const float* afw = (const float*)d_in[1];
  const float* gnw = (const float*)d_in[2];
  const float* gnb = (const float*)d_in[3];
  const float* w1  = (const float*)d_in[4];
  const float* w3  = (const float*)d_in[5];
  const float* w5  = (const float*)d_in[6];
  const float* scw = (const float*)d_in[7];
  const float* cgw = (const float*)d_in[8];
  const float* spw = (const float*)d_in[9];

  char* ws = (char*)d_ws;
  float* sig_h = (float*)(ws + 0);               // 1 MiB
  float* sig_w = (float*)(ws + 1048576);         // 1 MiB
  float* Agn   = (float*)(ws + 2097152);         // 8 KiB
  float* Bgn   = (float*)(ws + 2105344);         // 8 KiB
  float* gacc  = (float*)(ws + 2113536);         // 32 KiB
  float* a1a2  = (float*)(ws + 2146304);         // 16 KiB (aliases w5s: w5s dead before kT writes)
  float* w5s   = (float*)(ws + 2146304);         // 6.4 KiB, lives kW..kC only
  unsigned short* x1m = (unsigned short*)(ws + 2162688);            // 64 MiB
  unsigned short* x2m = (unsigned short*)(ws + 2162688 + 67108864); // 64 MiB
  float* out = (float*)d_out;
  // xh/xw staging lives in d_out (dead before kF writes it)
  float* xh_ws = (float*)d_out;                  // 1 MiB
  float* xw_ws = (float*)d_out + 262144;         // 1 MiB

  hipMemsetAsync(gacc, 0, NN*32*sizeof(float), stream);
  kW <<<7, 256, 0, stream>>>(w5, scw, w5s);
  kA1<<<NN*CG, 256, 0, stream>>>(x, xh_ws, xw_ws);
  kA2<<<NN, 256, 0, stream>>>(xh_ws, xw_ws, afw, sig_h, sig_w);
  kB <<<NN*CG, 256, 0, stream>>>(x, sig_h, sig_w, gnw, gnb, Agn, Bgn);
  kC <<<NN*16, 256, 0, stream>>>(x, w1, w3, w5s, scw, spw, sig_h, sig_w, Agn, Bgn, x1m, x2m, gacc);
  kT <<<4, 64, 0, stream>>>(gacc, cgw, a1a2);
  kF <<<NN*64, 256, 0, stream>>>(x, x1m, x2m, a1a2, spw, out);
}

// Round 3
// 486.581 us; speedup vs baseline: 1.2645x; 1.0416x over previous
//
#include <hip/hip_runtime.h>
#include <math.h>

#define HH 128
#define WW 128
#define CG 8
#define NN 256
#define HWSZ (HH*WW)

typedef __bf16 bf16x8 __attribute__((ext_vector_type(8)));
typedef short short8v __attribute__((ext_vector_type(8)));
typedef float f32x4 __attribute__((ext_vector_type(4)));

__device__ __forceinline__ float sigmoidf_(float x){ return 1.0f/(1.0f+__expf(-x)); }

__device__ __forceinline__ unsigned short f2bf(float x){
  __bf16 h = (__bf16)x;
  return __builtin_bit_cast(unsigned short, h);
}
__device__ __forceinline__ float bf2f(unsigned short h){
  union { unsigned u; float f; } v; v.u = ((unsigned)h) << 16; return v.f;
}

// ---------------- Kernel W: pre-scale 5x5 weights by softmax(scale_w)[2] -------
__global__ void kW(const float* __restrict__ w5, const float* __restrict__ scw,
                   float* __restrict__ w5s){
  int i = blockIdx.x*256 + threadIdx.x;
  if (i >= CG*CG*25) return;
  float a = scw[0], b = scw[1], c = scw[2];
  float m = fmaxf(a, fmaxf(b, c));
  float e0 = __expf(a-m), e1 = __expf(b-m), e2 = __expf(c-m);
  float sw2 = e2 / (e0+e1+e2);
  w5s[i] = sw2 * w5[i];
}

// ---------------- Kernel A1: per-(n,c) row & column means ----------------------
__global__ __launch_bounds__(256) void kA1(const float* __restrict__ gx,
                                           float* __restrict__ xh_ws,
                                           float* __restrict__ xw_ws){
  int b = blockIdx.x; int n = b >> 3; int c = b & 7;
  int tid = threadIdx.x;
  __shared__ float colpart[2][WW];
  const float* img = gx + (size_t)(n*CG+c)*HWSZ;
  int w = tid & 127, half = tid >> 7;
  float acc = 0.f;
  const float* p = img + half*64*WW + w;
  for (int h = 0; h < 64; ++h) acc += p[h*WW];
  colpart[half][w] = acc;
  int h2 = tid >> 1, wh = tid & 1;
  float racc = 0.f;
  const float* rp = img + h2*WW + wh*64;
  for (int j = 0; j < 64; ++j) racc += rp[j];
  racc += __shfl_xor(racc, 1);
  __syncthreads();
  if (tid < WW) xw_ws[(n*CG+c)*WW + tid] = (colpart[0][tid] + colpart[1][tid]) * (1.0f/HH);
  if (wh == 0) xh_ws[(n*CG+c)*HH + h2] = racc * (1.0f/WW);
}

// ---------------- Kernel A2: 8x8 fuse conv + sigmoid ---------------------------
__global__ __launch_bounds__(256) void kA2(const float* __restrict__ xh_ws,
                                           const float* __restrict__ xw_ws,
                                           const float* __restrict__ afw,
                                           float* __restrict__ sig_h,
                                           float* __restrict__ sig_w){
  int n = blockIdx.x;
  int tid = threadIdx.x;
  if (tid < HH){
    int h = tid;
    float v[CG];
    #pragma unroll
    for (int c = 0; c < CG; ++c) v[c] = xh_ws[(n*CG+c)*HH + h];
    #pragma unroll
    for (int o = 0; o < CG; ++o){
      float s = 0.f;
      #pragma unroll
      for (int i = 0; i < CG; ++i) s = fmaf(afw[o*CG+i], v[i], s);
      sig_h[(n*CG+o)*HH + h] = sigmoidf_(s);
    }
  } else {
    int w = tid - 128;
    float v[CG];
    #pragma unroll
    for (int c = 0; c < CG; ++c) v[c] = xw_ws[(n*CG+c)*WW + w];
    #pragma unroll
    for (int o = 0; o < CG; ++o){
      float s = 0.f;
      #pragma unroll
      for (int i = 0; i < CG; ++i) s = fmaf(afw[o*CG+i], v[i], s);
      sig_w[(n*CG+o)*WW + w] = sigmoidf_(s);
    }
  }
}

// ---------------- Kernel B: GroupNorm stats of t = gx*sigh*sigw ----------------
__global__ __launch_bounds__(256) void kB(const float* __restrict__ gx,
                                          const float* __restrict__ sig_h,
                                          const float* __restrict__ sig_w,
                                          const float* __restrict__ gn_w,
                                          const float* __restrict__ gn_b,
                                          float* __restrict__ Agn,
                                          float* __restrict__ Bgn){
  int b = blockIdx.x; int n = b >> 3; int c = b & 7;
  int tid = threadIdx.x;
  __shared__ float sh[HH];
  __shared__ float swv[WW];
  __shared__ float red[16];
  if (tid < HH) sh[tid] = sig_h[(n*CG+c)*HH + tid];
  else          swv[tid-128] = sig_w[(n*CG+c)*WW + tid - 128];
  __syncthreads();
  const float* img = gx + (size_t)(n*CG+c)*HWSZ;
  float s1 = 0.f, s2 = 0.f;
  for (int idx = tid; idx < HWSZ; idx += 256){
    int h = idx >> 7, w = idx & 127;
    float t = img[idx] * sh[h] * swv[w];
    s1 += t; s2 = fmaf(t, t, s2);
  }
  #pragma unroll
  for (int off = 32; off; off >>= 1){ s1 += __shfl_down(s1, off); s2 += __shfl_down(s2, off); }
  int wv = tid >> 6, ln = tid & 63;
  if (ln == 0){ red[wv] = s1; red[8+wv] = s2; }
  __syncthreads();
  if (tid == 0){
    float S1 = red[0]+red[1]+red[2]+red[3];
    float S2 = red[8]+red[9]+red[10]+red[11];
    float mu  = S1 * (1.0f/HWSZ);
    float var = S2 * (1.0f/HWSZ) - mu*mu;
    float rstd = rsqrtf(var + 1e-5f);
    float A = rstd * gn_w[c];
    Agn[n*CG+c] = A;
    Bgn[n*CG+c] = gn_b[c] - mu*A;
  }
}

// ---------------- Kernel C: MFMA implicit-GEMM fused convs ---------------------
// N=16 cols: 0..7 = x1 conv path with sw1*w3 FOLDED IN (hi), 8..15 = raw 3x3.
// Lo-matrix accQ: cols 0..7 = lo-correction of x1 weights; col 8 = sp-gate d1
// weights (spw . W1c); col 9 = sp-gate d2 weights (spw . w3). Gate scalars land
// in lanes 8/9 of each pixel-quad -> one shuffle broadcast per reg.
// Staging: one pass, 8-ic vector per pixel, ds_write_b128 contiguous (no bank
// conflicts). Gated-tile build: b128 read + b128 write, contiguous.
__global__ __launch_bounds__(256) void kC(const float* __restrict__ gx,
                                          const float* __restrict__ w1,
                                          const float* __restrict__ w3,
                                          const float* __restrict__ w5s,
                                          const float* __restrict__ scale_w,
                                          const float* __restrict__ spw,
                                          const float* __restrict__ sig_h,
                                          const float* __restrict__ sig_w,
                                          const float* __restrict__ Agn,
                                          const float* __restrict__ Bgn,
                                          unsigned short* __restrict__ x1m,
                                          unsigned short* __restrict__ x2m,
                                          float* __restrict__ gacc){
  // rows 0..35: raw 36x36 haloed tile; rows 36..67: gated center (cols 2..33)
  __shared__ __align__(16) unsigned short tile[68*36*8];   // 39168 B
  __shared__ __align__(16) unsigned short Bm[7][16][32];   // 7168 B (hi)
  __shared__ __align__(16) unsigned short BmLo[7][10][32]; // 4480 B (lo + gate cols)
  __shared__ float sighs[CG][32];
  __shared__ float sigws[CG][32];
  __shared__ float constA[CG];
  __shared__ float wred[4][32];

  int tid = threadIdx.x;
  int bb = blockIdx.x;
  int n  = bb >> 4;
  int t_ = bb & 15;
  int y0 = (t_ >> 2) * 32;
  int x0 = (t_ & 3) * 32;

  float sw0, sw1;
  {
    float a = scale_w[0], b = scale_w[1], c = scale_w[2];
    float m = fmaxf(a, fmaxf(b, c));
    float e0 = __expf(a-m), e1 = __expf(b-m), e2 = __expf(c-m);
    float inv = 1.0f/(e0+e1+e2);
    sw0 = e0*inv; sw1 = e1*inv;
  }
  {
    int ic = tid >> 5, k = tid & 31;
    sighs[ic][k] = sig_h[(n*CG+ic)*HH + y0 + k];
    sigws[ic][k] = sig_w[(n*CG+ic)*WW + x0 + k];
  }
  if (tid < CG){
    float s = 0.f;
    #pragma unroll
    for (int i = 0; i < CG; ++i) s = fmaf(w1[tid*CG+i], Bgn[n*CG+i], s);
    constA[tid] = sw0 * s;
  }

  // ---- stage raw 36x36 halo tile: 8-ic vector per pixel, one b128 write ------
  const float* base_n = gx + (size_t)n*CG*HWSZ;
  for (int e = tid; e < 1296; e += 256){
    int yy = e / 36, xx = e - yy*36;
    int gy = y0 + yy - 2, gz = x0 + xx - 2;
    uint4 pk;
    unsigned* pw = (unsigned*)&pk;
    if ((unsigned)gy < HH && (unsigned)gz < WW){
      int o = gy*WW + gz;
      #pragma unroll
      for (int p = 0; p < 4; ++p){
        float v0 = base_n[(size_t)(2*p)*HWSZ + o];
        float v1 = base_n[(size_t)(2*p+1)*HWSZ + o];
        pw[p] = (unsigned)f2bf(v0) | ((unsigned)f2bf(v1) << 16);
      }
    } else {
      pw[0] = pw[1] = pw[2] = pw[3] = 0u;
    }
    *reinterpret_cast<uint4*>(&tile[e*8]) = pk;
  }

  // ---- build B matrices ------------------------------------------------------
  for (int e = tid; e < 3584; e += 256){
    int s   = e >> 9;
    int rem = e & 511;
    int nn = rem >> 5, kk = rem & 31;
    int tap = s*4 + (kk >> 3);
    int ic  = kk & 7;
    int ky = tap/5, kx = tap - ky*5;
    bool in3 = (tap < 25) && (ky >= 1) && (ky <= 3) && (kx >= 1) && (kx <= 3);
    float wv = 0.f;
    if (nn < 8){
      if (tap < 25){
        wv = w5s[nn*200 + ic*25 + tap];
        if (in3) wv = fmaf(sw1, w3[nn*72 + ic*9 + (ky-1)*3 + (kx-1)], wv);
      } else if (tap == 25){
        wv = sw0 * w1[nn*CG + ic] * Agn[n*CG + ic];
      }
      unsigned short hi = f2bf(wv);
      Bm[s][nn][kk]   = hi;
      BmLo[s][nn][kk] = f2bf(wv - bf2f(hi));
    } else {
      if (in3) wv = w3[(nn-8)*72 + ic*9 + (ky-1)*3 + (kx-1)];
      Bm[s][nn][kk] = f2bf(wv);
    }
  }
  // gate columns: BmLo rows 8 (d1 = spw . W1c) and 9 (d2 = spw . w3)
  for (int e = tid; e < 448; e += 256){
    int s   = e >> 6;
    int rem = e & 63;
    int col = rem >> 5;
    int kk  = rem & 31;
    int tap = s*4 + (kk >> 3);
    int ic  = kk & 7;
    int ky = tap/5, kx = tap - ky*5;
    bool in3 = (tap < 25) && (ky >= 1) && (ky <= 3) && (kx >= 1) && (kx <= 3);
    float sum = 0.f;
    #pragma unroll
    for (int oc = 0; oc < 8; ++oc){
      float wv = 0.f;
      if (col == 0){
        if (tap < 25){
          wv = w5s[oc*200 + ic*25 + tap];
          if (in3) wv = fmaf(sw1, w3[oc*72 + ic*9 + (ky-1)*3 + (kx-1)], wv);
        } else if (tap == 25){
          wv = sw0 * w1[oc*CG + ic] * Agn[n*CG + ic];
        }
      } else {
        if (in3) wv = w3[oc*72 + ic*9 + (ky-1)*3 + (kx-1)];
      }
      sum = fmaf(spw[oc], wv, sum);
    }
    BmLo[s][8+col][kk] = f2bf(sum);
  }
  __syncthreads();

  // ---- gated center tile (t = raw*sigh*sigw): b128 read/modify/write --------
  for (int e = tid; e < 1024; e += 256){
    int yl = e >> 5, xl = e & 31;
    uint4 pk = *reinterpret_cast<const uint4*>(&tile[((yl+2)*36 + (xl+2))*8]);
    unsigned* pw = (unsigned*)&pk;
    #pragma unroll
    for (int p = 0; p < 4; ++p){
      float g0 = sighs[2*p][yl]   * sigws[2*p][xl];
      float g1 = sighs[2*p+1][yl] * sigws[2*p+1][xl];
      float v0 = bf2f((unsigned short)(pw[p] & 0xffffu)) * g0;
      float v1 = bf2f((unsigned short)(pw[p] >> 16))     * g1;
      pw[p] = (unsigned)f2bf(v0) | ((unsigned)f2bf(v1) << 16);
    }
    *reinterpret_cast<uint4*>(&tile[((yl+36)*36 + (xl+2))*8]) = pk;
  }

  // ---- per-lane B fragments and tap address offsets --------------------------
  int lane = tid & 63;
  int wid  = tid >> 6;
  int pr = lane & 15;   // A-role: pixel row; B/D-role: output column n
  int tg = lane >> 4;   // k-block (tap within step); D-role: pixel quad
  short8v zs = {0,0,0,0,0,0,0,0};
  bf16x8 zb = __builtin_bit_cast(bf16x8, zs);
  bf16x8 bH[7], bL[7];
  int ofs[7];
  #pragma unroll
  for (int s = 0; s < 7; ++s){
    bH[s] = *reinterpret_cast<const bf16x8*>(&Bm[s][pr][tg*8]);
    bL[s] = (pr < 10) ? *reinterpret_cast<const bf16x8*>(&BmLo[s][pr][tg*8]) : zb;
    int t = s*4 + tg;
    int ky, kx;
    if (t < 25){ ky = t/5; kx = t - ky*5; }
    else if (t == 25){ ky = 36; kx = 2; }   // gated tile alias
    else { ky = 0; kx = 0; }                // dummy taps (B=0)
    ofs[s] = (ky*36 + kx)*8;
  }
  float Cd1 = 0.f;
  #pragma unroll
  for (int oc = 0; oc < CG; ++oc) Cd1 = fmaf(spw[oc], constA[oc], Cd1);
  __syncthreads();

  float cA   = (pr < 8) ? constA[pr] : 0.f;
  int  gsrc  = (lane & 48) | (pr < 8 ? 8 : 9);
  float sAcc = 0.f, qAcc = 0.f;  // lanes pr<8: (s1,qq1); pr>=8: (s2,qq2)

  #pragma unroll 2
  for (int i = 0; i < 16; ++i){
    int mb = wid*16 + i;
    int yl = mb >> 1;
    int xh = (mb & 1) << 4;
    const unsigned short* abase = &tile[(yl*36 + xh + pr)*8];
    f32x4 accP = {0.f,0.f,0.f,0.f};
    f32x4 accQ = {0.f,0.f,0.f,0.f};
    #pragma unroll
    for (int s = 0; s < 7; ++s){
      bf16x8 a = *reinterpret_cast<const bf16x8*>(abase + ofs[s]);
      accP = __builtin_amdgcn_mfma_f32_16x16x32_bf16(a, bH[s], accP, 0, 0, 0);
      accQ = __builtin_amdgcn_mfma_f32_16x16x32_bf16(a, bL[s], accQ, 0, 0, 0);
    }
    // D layout: lane holds D[pixel = tg*4 + r][col = pr]
    float gq[4];
    #pragma unroll
    for (int r = 0; r < 4; ++r) gq[r] = __shfl(accQ[r], gsrc);
    ushort4 u;
    #pragma unroll
    for (int r = 0; r < 4; ++r){
      float vvr = (pr < 8) ? (accP[r] + accQ[r] + cA) : accP[r];
      float d   = (pr < 8) ? (gq[r] + Cd1) : gq[r];
      float sg  = sigmoidf_(d);
      sAcc += vvr;
      qAcc = fmaf(vvr, sg, qAcc);
      ((unsigned short*)&u)[r] = f2bf(vvr);
    }
    int gy  = y0 + yl;
    int gxx = x0 + xh + tg*4;
    size_t off = ((size_t)(n*CG + (pr & 7))*HH + gy)*WW + gxx;
    if (pr < 8) *reinterpret_cast<ushort4*>(x1m + off) = u;
    else        *reinterpret_cast<ushort4*>(x2m + off) = u;
  }

  sAcc += __shfl_xor(sAcc, 16); sAcc += __shfl_xor(sAcc, 32);
  qAcc += __shfl_xor(qAcc, 16); qAcc += __shfl_xor(qAcc, 32);
  if (lane < 16){
    int b0 = (pr < 8) ? pr : (8 + pr);
    wred[wid][b0]     = sAcc;
    wred[wid][b0 + 8] = qAcc;
  }
  __syncthreads();
  if (tid < 32){
    float s = wred[0][tid] + wred[1][tid] + wred[2][tid] + wred[3][tid];
    atomicAdd(&gacc[n*32 + tid], s);
  }
}

// ---------------- Kernel T: channel gates + softmaxes -> a1,a2 -----------------
__global__ void kT(const float* __restrict__ gacc, const float* __restrict__ cgw,
                   float* __restrict__ a1a2){
  int n = blockIdx.x*blockDim.x + threadIdx.x;
  if (n >= NN) return;
  const float* g = gacc + n*32;
  float m1[CG], q1[CG], m2[CG], q2[CG];
  #pragma unroll
  for (int c = 0; c < CG; ++c){
    m1[c] = g[c]      * (1.0f/HWSZ);
    q1[c] = g[8+c]    * (1.0f/HWSZ);
    m2[c] = g[16+c]   * (1.0f/HWSZ);
    q2[c] = g[24+c]   * (1.0f/HWSZ);
  }
  float chg1[CG], chg2[CG];
  #pragma unroll
  for (int o = 0; o < CG; ++o){
    float s1 = 0.f, s2 = 0.f;
    #pragma unroll
    for (int i = 0; i < CG; ++i){ s1 = fmaf(cgw[o*CG+i], m1[i], s1); s2 = fmaf(cgw[o*CG+i], m2[i], s2); }
    chg1[o] = sigmoidf_(s1); chg2[o] = sigmoidf_(s2);
  }
  float z1[CG], z2[CG];
  float mx1 = -1e30f, mx2 = -1e30f;
  #pragma unroll
  for (int c = 0; c < CG; ++c){
    z1[c] = chg1[c]*q1[c]; z2[c] = chg2[c]*q2[c];
    mx1 = fmaxf(mx1, z1[c]); mx2 = fmaxf(mx2, z2[c]);
  }
  float su1 = 0.f, su2 = 0.f;
  #pragma unroll
  for (int c = 0; c < CG; ++c){
    z1[c] = __expf(z1[c]-mx1); su1 += z1[c];
    z2[c] = __expf(z2[c]-mx2); su2 += z2[c];
  }
  float i1 = 1.0f/su1, i2 = 1.0f/su2;
  #pragma unroll
  for (int c = 0; c < CG; ++c){
    float x11 = z1[c]*i1;
    float x21 = z2[c]*i2;
    a1a2[n*16 + c]     = x21 * chg1[c];
    a1a2[n*16 + 8 + c] = x11 * chg2[c];
  }
}

// ---------------- Kernel F: final weights + output (4 px/thread) ---------------
__global__ __launch_bounds__(256) void kF(const float* __restrict__ gx,
                                          const unsigned short* __restrict__ x1m,
                                          const unsigned short* __restrict__ x2m,
                                          const float* __restrict__ a1a2,
                                          const float* __restrict__ spw,
                                          float* __restrict__ out){
  int tid = threadIdx.x;
  int bb = blockIdx.x;            // grid NN*16
  int n  = bb >> 4;
  int hw = ((bb & 15) << 10) + tid*4;
  size_t base = (size_t)(n*CG)*HWSZ + hw;
  float a1[CG], a2[CG], sp[CG];
  #pragma unroll
  for (int c = 0; c < CG; ++c){
    a1[c] = a1a2[n*16 + c];
    a2[c] = a1a2[n*16 + 8 + c];
    sp[c] = spw[c];
  }
  float d1[4]  = {0.f,0.f,0.f,0.f}, dd1[4] = {0.f,0.f,0.f,0.f};
  float d2[4]  = {0.f,0.f,0.f,0.f}, dd2[4] = {0.f,0.f,0.f,0.f};
  #pragma unroll
  for (int c = 0; c < CG; ++c){
    ushort4 u1 = *reinterpret_cast<const ushort4*>(x1m + base + (size_t)c*HWSZ);
    ushort4 u2 = *reinterpret_cast<const ushort4*>(x2m + base + (size_t)c*HWSZ);
    #pragma unroll
    for (int p = 0; p < 4; ++p){
      float v1 = bf2f(((const unsigned short*)&u1)[p]);
      float v2 = bf2f(((const unsigned short*)&u2)[p]);
      d1[p]  = fmaf(sp[c], v1, d1[p]);  dd1[p] = fmaf(a1[c], v1, dd1[p]);
      d2[p]  = fmaf(sp[c], v2, d2[p]);  dd2[p] = fmaf(a2[c], v2, dd2[p]);
    }
  }
  float sW[4];
  #pragma unroll
  for (int p = 0; p < 4; ++p){
    float Wv = sigmoidf_(d1[p])*dd1[p] + sigmoidf_(d2[p])*dd2[p];
    sW[p] = sigmoidf_(Wv);
  }
  #pragma unroll
  for (int c = 0; c < CG; ++c){
    float4 g = *reinterpret_cast<const float4*>(gx + base + (size_t)c*HWSZ);
    float4 o;
    o.x = g.x*sW[0]; o.y = g.y*sW[1]; o.z = g.z*sW[2]; o.w = g.w*sW[3];
    *reinterpret_cast<float4*>(out + base + (size_t)c*HWSZ) = o;
  }
}

extern "C" void kernel_launch(void* const* d_in, const int* in_sizes, int n_in,
                              void* d_out, int out_size, void* d_ws, size_t ws_size,
                              hipStream_t stream){
  const float* x   = (const float*)d_in[0];
  const float* afw = (const float*)d_in[1];
  const float* gnw = (const float*)d_in[2];
  const float* gnb = (const float*)d_in[3];
  const float* w1  = (const float*)d_in[4];
  const float* w3  = (const float*)d_in[5];
  const float* w5  = (const float*)d_in[6];
  const float* scw = (const float*)d_in[7];
  const float* cgw = (const float*)d_in[8];
  const float* spw = (const float*)d_in[9];

  char* ws = (char*)d_ws;
  float* sig_h = (float*)(ws + 0);               // 1 MiB
  float* sig_w = (float*)(ws + 1048576);         // 1 MiB
  float* Agn   = (float*)(ws + 2097152);         // 8 KiB
  float* Bgn   = (float*)(ws + 2105344);         // 8 KiB
  float* gacc  = (float*)(ws + 2113536);         // 32 KiB
  float* a1a2  = (float*)(ws + 2146304);         // 16 KiB (aliases w5s: w5s dead before kT writes)
  float* w5s   = (float*)(ws + 2146304);         // 6.4 KiB, lives kW..kC only
  unsigned short* x1m = (unsigned short*)(ws + 2162688);            // 64 MiB
  unsigned short* x2m = (unsigned short*)(ws + 2162688 + 67108864); // 64 MiB
  float* out = (float*)d_out;
  // xh/xw staging lives in d_out (dead before kF writes it)
  float* xh_ws = (float*)d_out;                  // 1 MiB
  float* xw_ws = (float*)d_out + 262144;         // 1 MiB

  hipMemsetAsync(gacc, 0, NN*32*sizeof(float), stream);
  kW <<<7, 256, 0, stream>>>(w5, scw, w5s);
  kA1<<<NN*CG, 256, 0, stream>>>(x, xh_ws, xw_ws);
  kA2<<<NN, 256, 0, stream>>>(xh_ws, xw_ws, afw, sig_h, sig_w);
  kB <<<NN*CG, 256, 0, stream>>>(x, sig_h, sig_w, gnw, gnb, Agn, Bgn);
  kC <<<NN*16, 256, 0, stream>>>(x, w1, w3, w5s, scw, spw, sig_h, sig_w, Agn, Bgn, x1m, x2m, gacc);
  kT <<<4, 64, 0, stream>>>(gacc, cgw, a1a2);
  kF <<<NN*16, 256, 0, stream>>>(x, x1m, x2m, a1a2, spw, out);
}

// Round 4
// 447.097 us; speedup vs baseline: 1.3761x; 1.0883x over previous
//
#include <hip/hip_runtime.h>
#include <math.h>

#define HH 128
#define WW 128
#define CG 8
#define NN 256
#define HWSZ (HH*WW)
#define GB (36*36*8)   // gated-tile base offset (ushort units)

typedef __bf16 bf16x8 __attribute__((ext_vector_type(8)));
typedef short short8v __attribute__((ext_vector_type(8)));
typedef float f32x4 __attribute__((ext_vector_type(4)));

__device__ __forceinline__ float sigmoidf_(float x){ return 1.0f/(1.0f+__expf(-x)); }

__device__ __forceinline__ unsigned short f2bf(float x){
  __bf16 h = (__bf16)x;
  return __builtin_bit_cast(unsigned short, h);
}
__device__ __forceinline__ float bf2f(unsigned short h){
  union { unsigned u; float f; } v; v.u = ((unsigned)h) << 16; return v.f;
}

// x1-path weight (w5*sw2 + folded sw1*w3, tap25 = sw0*w1 — Agn folded into tile)
__device__ __forceinline__ float wx1_(const float* w1, const float* w3, const float* w5,
                                      float sw0, float sw1, float sw2,
                                      int oc, int ic, int tap){
  if (tap < 25){
    int ky = tap/5, kx = tap - ky*5;
    float wv = sw2 * w5[oc*200 + ic*25 + tap];
    if (ky >= 1 && ky <= 3 && kx >= 1 && kx <= 3)
      wv = fmaf(sw1, w3[oc*72 + ic*9 + (ky-1)*3 + (kx-1)], wv);
    return wv;
  }
  if (tap == 25) return sw0 * w1[oc*CG + ic];
  return 0.f;
}
__device__ __forceinline__ float wx2_(const float* w3, int oc, int ic, int tap){
  if (tap < 25){
    int ky = tap/5, kx = tap - ky*5;
    if (ky >= 1 && ky <= 3 && kx >= 1 && kx <= 3)
      return w3[oc*72 + ic*9 + (ky-1)*3 + (kx-1)];
  }
  return 0.f;
}

// ---------------- Kernel WB: precompute n-independent B tensors ----------------
// BH[s][16][32] (hi): cols 0..7 x1-path, 8..15 raw 3x3.
// BL[s][10][32]: rows 0..7 lo-correction of x1 weights; row 8 = spw.x1w (gate d1);
// row 9 = spw.w3 (gate d2).
__global__ void kWB(const float* __restrict__ w1, const float* __restrict__ w3,
                    const float* __restrict__ w5, const float* __restrict__ scw,
                    const float* __restrict__ spw,
                    unsigned short* __restrict__ BH, unsigned short* __restrict__ BL){
  int e = blockIdx.x*256 + threadIdx.x;
  float a = scw[0], b = scw[1], c = scw[2];
  float m = fmaxf(a, fmaxf(b, c));
  float e0 = __expf(a-m), e1 = __expf(b-m), e2 = __expf(c-m);
  float inv = 1.0f/(e0+e1+e2);
  float sw0 = e0*inv, sw1 = e1*inv, sw2 = e2*inv;
  if (e < 3584){
    int s = e >> 9, rem = e & 511, nn = rem >> 5, kk = rem & 31;
    int tap = s*4 + (kk >> 3), ic = kk & 7;
    float wv = (nn < 8) ? wx1_(w1,w3,w5,sw0,sw1,sw2,nn,ic,tap)
                        : wx2_(w3,nn-8,ic,tap);
    BH[e] = f2bf(wv);
  } else if (e < 5824){
    int e2 = e - 3584;
    int s = e2 / 320, rem = e2 - s*320, nn = rem >> 5, kk = rem & 31;
    int tap = s*4 + (kk >> 3), ic = kk & 7;
    float outv;
    if (nn < 8){
      float wv = wx1_(w1,w3,w5,sw0,sw1,sw2,nn,ic,tap);
      outv = wv - bf2f(f2bf(wv));
    } else {
      float sum = 0.f;
      #pragma unroll
      for (int oc = 0; oc < CG; ++oc){
        float wv = (nn == 8) ? wx1_(w1,w3,w5,sw0,sw1,sw2,oc,ic,tap)
                             : wx2_(w3,oc,ic,tap);
        sum = fmaf(spw[oc], wv, sum);
      }
      outv = sum;
    }
    BL[e2] = f2bf(outv);
  }
}

// ---------------- Kernel A1: per-(n,c) row & column means ----------------------
__global__ __launch_bounds__(256) void kA1(const float* __restrict__ gx,
                                           float* __restrict__ xh_ws,
                                           float* __restrict__ xw_ws){
  int b = blockIdx.x; int n = b >> 3; int c = b & 7;
  int tid = threadIdx.x;
  __shared__ float colpart[2][WW];
  const float* img = gx + (size_t)(n*CG+c)*HWSZ;
  int w = tid & 127, half = tid >> 7;
  float acc = 0.f;
  const float* p = img + half*64*WW + w;
  for (int h = 0; h < 64; ++h) acc += p[h*WW];
  colpart[half][w] = acc;
  int h2 = tid >> 1, wh = tid & 1;
  float racc = 0.f;
  const float* rp = img + h2*WW + wh*64;
  for (int j = 0; j < 64; ++j) racc += rp[j];
  racc += __shfl_xor(racc, 1);
  __syncthreads();
  if (tid < WW) xw_ws[(n*CG+c)*WW + tid] = (colpart[0][tid] + colpart[1][tid]) * (1.0f/HH);
  if (wh == 0) xh_ws[(n*CG+c)*HH + h2] = racc * (1.0f/WW);
}

// ---------------- Kernel A2: 8x8 fuse conv + sigmoid ---------------------------
__global__ __launch_bounds__(256) void kA2(const float* __restrict__ xh_ws,
                                           const float* __restrict__ xw_ws,
                                           const float* __restrict__ afw,
                                           float* __restrict__ sig_h,
                                           float* __restrict__ sig_w){
  int n = blockIdx.x;
  int tid = threadIdx.x;
  if (tid < HH){
    int h = tid;
    float v[CG];
    #pragma unroll
    for (int c = 0; c < CG; ++c) v[c] = xh_ws[(n*CG+c)*HH + h];
    #pragma unroll
    for (int o = 0; o < CG; ++o){
      float s = 0.f;
      #pragma unroll
      for (int i = 0; i < CG; ++i) s = fmaf(afw[o*CG+i], v[i], s);
      sig_h[(n*CG+o)*HH + h] = sigmoidf_(s);
    }
  } else {
    int w = tid - 128;
    float v[CG];
    #pragma unroll
    for (int c = 0; c < CG; ++c) v[c] = xw_ws[(n*CG+c)*WW + w];
    #pragma unroll
    for (int o = 0; o < CG; ++o){
      float s = 0.f;
      #pragma unroll
      for (int i = 0; i < CG; ++i) s = fmaf(afw[o*CG+i], v[i], s);
      sig_w[(n*CG+o)*WW + w] = sigmoidf_(s);
    }
  }
}

// ---------------- Kernel B: GroupNorm stats; writes Bgn + sighA = sigh*Agn -----
__global__ __launch_bounds__(256) void kB(const float* __restrict__ gx,
                                          const float* __restrict__ sig_h,
                                          const float* __restrict__ sig_w,
                                          const float* __restrict__ gn_w,
                                          const float* __restrict__ gn_b,
                                          float* __restrict__ Bgn,
                                          float* __restrict__ sighA){
  int b = blockIdx.x; int n = b >> 3; int c = b & 7;
  int tid = threadIdx.x;
  __shared__ float sh[HH];
  __shared__ float swv[WW];
  __shared__ float red[16];
  __shared__ float sAb;
  if (tid < HH) sh[tid] = sig_h[(n*CG+c)*HH + tid];
  else          swv[tid-128] = sig_w[(n*CG+c)*WW + tid - 128];
  __syncthreads();
  const float* img = gx + (size_t)(n*CG+c)*HWSZ;
  float s1 = 0.f, s2 = 0.f;
  for (int idx = tid; idx < HWSZ; idx += 256){
    int h = idx >> 7, w = idx & 127;
    float t = img[idx] * sh[h] * swv[w];
    s1 += t; s2 = fmaf(t, t, s2);
  }
  #pragma unroll
  for (int off = 32; off; off >>= 1){ s1 += __shfl_down(s1, off); s2 += __shfl_down(s2, off); }
  int wv = tid >> 6, ln = tid & 63;
  if (ln == 0){ red[wv] = s1; red[8+wv] = s2; }
  __syncthreads();
  if (tid == 0){
    float S1 = red[0]+red[1]+red[2]+red[3];
    float S2 = red[8]+red[9]+red[10]+red[11];
    float mu  = S1 * (1.0f/HWSZ);
    float var = S2 * (1.0f/HWSZ) - mu*mu;
    float rstd = rsqrtf(var + 1e-5f);
    float A = rstd * gn_w[c];
    Bgn[n*CG+c] = gn_b[c] - mu*A;
    sAb = A;
  }
  __syncthreads();
  if (tid < HH) sighA[(n*CG+c)*HH + tid] = sh[tid] * sAb;
}

// ---------------- Kernel C: MFMA implicit-GEMM fused convs ---------------------
// B tensors precomputed (kWB), loaded per-lane from global (L2-hot).
// Agn folded into the gated tile (A-side). Fused staging writes raw halo tile
// (stride 36) + gated 32x32 tile (stride 32, base GB) in one pass.
// Pair-processing: each iteration computes both 16-pixel half-rows of a row,
// reusing B fragments (kept in VGPRs; never in LDS).
__global__ __launch_bounds__(256) void kC(const float* __restrict__ gx,
                                          const float* __restrict__ w1,
                                          const float* __restrict__ scale_w,
                                          const float* __restrict__ spw,
                                          const float* __restrict__ sig_w,
                                          const float* __restrict__ sighA,
                                          const float* __restrict__ Bgn,
                                          const unsigned short* __restrict__ BHg,
                                          const unsigned short* __restrict__ BLog,
                                          unsigned short* __restrict__ x1m,
                                          unsigned short* __restrict__ x2m,
                                          float* __restrict__ gacc){
  __shared__ __align__(16) unsigned short tile[36*36*8 + 32*32*8]; // 37120 B
  __shared__ float shf[CG*32];     // sigh*Agn, f32
  __shared__ float swf[CG*32];     // sigw, f32
  __shared__ float constA[CG];

  int tid = threadIdx.x;
  int bb = blockIdx.x;
  int n  = bb >> 4;
  int t_ = bb & 15;
  int y0 = (t_ >> 2) * 32;
  int x0 = (t_ & 3) * 32;

  int lane = tid & 63, wid = tid >> 6;
  int pr = lane & 15, tg = lane >> 4;

  // B fragments from global (coalesced 1 KiB/wave per step, L2-resident)
  bf16x8 bH[7], bL[7];
  #pragma unroll
  for (int s = 0; s < 7; ++s)
    bH[s] = *reinterpret_cast<const bf16x8*>(BHg + s*512 + pr*32 + tg*8);
  short8v zs = {0,0,0,0,0,0,0,0};
  bf16x8 zb = __builtin_bit_cast(bf16x8, zs);
  if (pr < 10){
    #pragma unroll
    for (int s = 0; s < 7; ++s)
      bL[s] = *reinterpret_cast<const bf16x8*>(BLog + s*320 + pr*32 + tg*8);
  } else {
    #pragma unroll
    for (int s = 0; s < 7; ++s) bL[s] = zb;
  }

  float sw0;
  {
    float a = scale_w[0], b = scale_w[1], c = scale_w[2];
    float m = fmaxf(a, fmaxf(b, c));
    float e0 = __expf(a-m), e1 = __expf(b-m), e2 = __expf(c-m);
    sw0 = e0 / (e0+e1+e2);
  }
  {
    int ic = tid >> 5, k = tid & 31;
    shf[ic*32+k] = sighA[(n*CG+ic)*HH + y0 + k];
    swf[ic*32+k] = sig_w[(n*CG+ic)*WW + x0 + k];
  }
  if (tid < CG){
    float s = 0.f;
    #pragma unroll
    for (int i = 0; i < CG; ++i) s = fmaf(w1[tid*CG+i], Bgn[n*CG+i], s);
    constA[tid] = sw0 * s;
  }
  __syncthreads();

  // fused staging: raw 36x36 halo tile + gated 32x32 center tile
  const float* base_n = gx + (size_t)n*CG*HWSZ;
  for (int e = tid; e < 1296; e += 256){
    int yy = e / 36, xx = e - yy*36;
    int gy = y0 + yy - 2, gz = x0 + xx - 2;
    float v[8];
    uint4 pk; unsigned* pw = (unsigned*)&pk;
    if ((unsigned)gy < HH && (unsigned)gz < WW){
      int o = gy*WW + gz;
      #pragma unroll
      for (int p = 0; p < 4; ++p){
        v[2*p]   = base_n[(size_t)(2*p)*HWSZ + o];
        v[2*p+1] = base_n[(size_t)(2*p+1)*HWSZ + o];
        pw[p] = (unsigned)f2bf(v[2*p]) | ((unsigned)f2bf(v[2*p+1]) << 16);
      }
    } else {
      #pragma unroll
      for (int p = 0; p < 4; ++p){ v[2*p] = 0.f; v[2*p+1] = 0.f; pw[p] = 0u; }
    }
    *reinterpret_cast<uint4*>(&tile[e*8]) = pk;
    int yl = yy - 2, xl = xx - 2;
    if ((unsigned)yl < 32u && (unsigned)xl < 32u){
      uint4 gk; unsigned* gw = (unsigned*)&gk;
      #pragma unroll
      for (int p = 0; p < 4; ++p){
        float t0 = v[2*p]   * shf[(2*p)*32   + yl] * swf[(2*p)*32   + xl];
        float t1 = v[2*p+1] * shf[(2*p+1)*32 + yl] * swf[(2*p+1)*32 + xl];
        gw[p] = (unsigned)f2bf(t0) | ((unsigned)f2bf(t1) << 16);
      }
      *reinterpret_cast<uint4*>(&tile[GB + (yl*32 + xl)*8]) = gk;
    }
  }

  // per-lane tap geometry (raw: stride 36 rows; gated: stride 32 rows at GB)
  int strd[7], ofs[7];
  #pragma unroll
  for (int s = 0; s < 7; ++s){
    int t = s*4 + tg;
    if (t < 25){ int ky = t/5, kx = t - ky*5; strd[s] = 36*8; ofs[s] = (ky*36 + kx)*8; }
    else if (t == 25){ strd[s] = 32*8; ofs[s] = GB; }
    else { strd[s] = 36*8; ofs[s] = 0; }   // dummy taps (B=0)
  }
  float Cd1 = 0.f;
  #pragma unroll
  for (int oc = 0; oc < CG; ++oc) Cd1 = fmaf(spw[oc], constA[oc], Cd1);
  float cA = (pr < 8) ? constA[pr] : 0.f;
  int gsrc = (lane & 48) | (pr < 8 ? 8 : 9);
  __syncthreads();

  float sAcc = 0.f, qAcc = 0.f;

#define EPI(P, Q, GXX) do { \
    float gq[4]; \
    _Pragma("unroll") \
    for (int r = 0; r < 4; ++r) gq[r] = __shfl(Q[r], gsrc); \
    ushort4 u; \
    _Pragma("unroll") \
    for (int r = 0; r < 4; ++r){ \
      float vvr = (pr < 8) ? (P[r] + Q[r] + cA) : P[r]; \
      float d   = (pr < 8) ? (gq[r] + Cd1) : gq[r]; \
      float sg  = sigmoidf_(d); \
      sAcc += vvr; \
      qAcc = fmaf(vvr, sg, qAcc); \
      ((unsigned short*)&u)[r] = f2bf(vvr); \
    } \
    size_t off = ((size_t)(n*CG + (pr & 7))*HH + (y0 + yl))*WW + (GXX); \
    if (pr < 8) *reinterpret_cast<ushort4*>(x1m + off) = u; \
    else        *reinterpret_cast<ushort4*>(x2m + off) = u; \
  } while(0)

  #pragma unroll 1
  for (int ii = 0; ii < 8; ++ii){
    int yl = wid*8 + ii;
    f32x4 P0 = {0.f,0.f,0.f,0.f}, Q0 = {0.f,0.f,0.f,0.f};
    f32x4 P1 = {0.f,0.f,0.f,0.f}, Q1 = {0.f,0.f,0.f,0.f};
    #pragma unroll
    for (int s = 0; s < 7; ++s){
      const unsigned short* ap = &tile[yl*strd[s] + ofs[s] + pr*8];
      bf16x8 a0 = *reinterpret_cast<const bf16x8*>(ap);
      bf16x8 a1 = *reinterpret_cast<const bf16x8*>(ap + 128);
      P0 = __builtin_amdgcn_mfma_f32_16x16x32_bf16(a0, bH[s], P0, 0, 0, 0);
      Q0 = __builtin_amdgcn_mfma_f32_16x16x32_bf16(a0, bL[s], Q0, 0, 0, 0);
      P1 = __builtin_amdgcn_mfma_f32_16x16x32_bf16(a1, bH[s], P1, 0, 0, 0);
      Q1 = __builtin_amdgcn_mfma_f32_16x16x32_bf16(a1, bL[s], Q1, 0, 0, 0);
    }
    EPI(P0, Q0, x0 + tg*4);
    EPI(P1, Q1, x0 + 16 + tg*4);
  }
#undef EPI

  sAcc += __shfl_xor(sAcc, 16); sAcc += __shfl_xor(sAcc, 32);
  qAcc += __shfl_xor(qAcc, 16); qAcc += __shfl_xor(qAcc, 32);
  if (lane < 16){
    int b0 = (pr < 8) ? pr : (8 + pr);
    atomicAdd(&gacc[n*32 + b0],     sAcc);
    atomicAdd(&gacc[n*32 + b0 + 8], qAcc);
  }
}

// ---------------- Kernel T: channel gates + softmaxes -> a1,a2 -----------------
__global__ void kT(const float* __restrict__ gacc, const float* __restrict__ cgw,
                   float* __restrict__ a1a2){
  int n = blockIdx.x*blockDim.x + threadIdx.x;
  if (n >= NN) return;
  const float* g = gacc + n*32;
  float m1[CG], q1[CG], m2[CG], q2[CG];
  #pragma unroll
  for (int c = 0; c < CG; ++c){
    m1[c] = g[c]      * (1.0f/HWSZ);
    q1[c] = g[8+c]    * (1.0f/HWSZ);
    m2[c] = g[16+c]   * (1.0f/HWSZ);
    q2[c] = g[24+c]   * (1.0f/HWSZ);
  }
  float chg1[CG], chg2[CG];
  #pragma unroll
  for (int o = 0; o < CG; ++o){
    float s1 = 0.f, s2 = 0.f;
    #pragma unroll
    for (int i = 0; i < CG; ++i){ s1 = fmaf(cgw[o*CG+i], m1[i], s1); s2 = fmaf(cgw[o*CG+i], m2[i], s2); }
    chg1[o] = sigmoidf_(s1); chg2[o] = sigmoidf_(s2);
  }
  float z1[CG], z2[CG];
  float mx1 = -1e30f, mx2 = -1e30f;
  #pragma unroll
  for (int c = 0; c < CG; ++c){
    z1[c] = chg1[c]*q1[c]; z2[c] = chg2[c]*q2[c];
    mx1 = fmaxf(mx1, z1[c]); mx2 = fmaxf(mx2, z2[c]);
  }
  float su1 = 0.f, su2 = 0.f;
  #pragma unroll
  for (int c = 0; c < CG; ++c){
    z1[c] = __expf(z1[c]-mx1); su1 += z1[c];
    z2[c] = __expf(z2[c]-mx2); su2 += z2[c];
  }
  float i1 = 1.0f/su1, i2 = 1.0f/su2;
  #pragma unroll
  for (int c = 0; c < CG; ++c){
    float x11 = z1[c]*i1;
    float x21 = z2[c]*i2;
    a1a2[n*16 + c]     = x21 * chg1[c];
    a1a2[n*16 + 8 + c] = x11 * chg2[c];
  }
}

// ---------------- Kernel F: final weights + output (4 px/thread) ---------------
__global__ __launch_bounds__(256) void kF(const float* __restrict__ gx,
                                          const unsigned short* __restrict__ x1m,
                                          const unsigned short* __restrict__ x2m,
                                          const float* __restrict__ a1a2,
                                          const float* __restrict__ spw,
                                          float* __restrict__ out){
  int tid = threadIdx.x;
  int bb = blockIdx.x;            // grid NN*16
  int n  = bb >> 4;
  int hw = ((bb & 15) << 10) + tid*4;
  size_t base = (size_t)(n*CG)*HWSZ + hw;
  float a1[CG], a2[CG], sp[CG];
  #pragma unroll
  for (int c = 0; c < CG; ++c){
    a1[c] = a1a2[n*16 + c];
    a2[c] = a1a2[n*16 + 8 + c];
    sp[c] = spw[c];
  }
  float d1[4]  = {0.f,0.f,0.f,0.f}, dd1[4] = {0.f,0.f,0.f,0.f};
  float d2[4]  = {0.f,0.f,0.f,0.f}, dd2[4] = {0.f,0.f,0.f,0.f};
  #pragma unroll
  for (int c = 0; c < CG; ++c){
    ushort4 u1 = *reinterpret_cast<const ushort4*>(x1m + base + (size_t)c*HWSZ);
    ushort4 u2 = *reinterpret_cast<const ushort4*>(x2m + base + (size_t)c*HWSZ);
    #pragma unroll
    for (int p = 0; p < 4; ++p){
      float v1 = bf2f(((const unsigned short*)&u1)[p]);
      float v2 = bf2f(((const unsigned short*)&u2)[p]);
      d1[p]  = fmaf(sp[c], v1, d1[p]);  dd1[p] = fmaf(a1[c], v1, dd1[p]);
      d2[p]  = fmaf(sp[c], v2, d2[p]);  dd2[p] = fmaf(a2[c], v2, dd2[p]);
    }
  }
  float sW[4];
  #pragma unroll
  for (int p = 0; p < 4; ++p){
    float Wv = sigmoidf_(d1[p])*dd1[p] + sigmoidf_(d2[p])*dd2[p];
    sW[p] = sigmoidf_(Wv);
  }
  #pragma unroll
  for (int c = 0; c < CG; ++c){
    float4 g = *reinterpret_cast<const float4*>(gx + base + (size_t)c*HWSZ);
    float4 o;
    o.x = g.x*sW[0]; o.y = g.y*sW[1]; o.z = g.z*sW[2]; o.w = g.w*sW[3];
    *reinterpret_cast<float4*>(out + base + (size_t)c*HWSZ) = o;
  }
}

extern "C" void kernel_launch(void* const* d_in, const int* in_sizes, int n_in,
                              void* d_out, int out_size, void* d_ws, size_t ws_size,
                              hipStream_t stream){
  const float* x   = (const float*)d_in[0];
  const float* afw = (const float*)d_in[1];
  const float* gnw = (const float*)d_in[2];
  const float* gnb = (const float*)d_in[3];
  const float* w1  = (const float*)d_in[4];
  const float* w3  = (const float*)d_in[5];
  const float* w5  = (const float*)d_in[6];
  const float* scw = (const float*)d_in[7];
  const float* cgw = (const float*)d_in[8];
  const float* spw = (const float*)d_in[9];

  char* ws = (char*)d_ws;
  float* sig_h = (float*)(ws + 0);                          // 1 MiB
  float* sig_w = (float*)(ws + 1048576);                    // 1 MiB
  unsigned short* BHg  = (unsigned short*)(ws + 2097152);   // 14336 B (16 KiB slot)
  float* a1a2 = (float*)(ws + 2097152);                     // 16 KiB, aliases BHg (BHg dead before kT)
  unsigned short* BLog = (unsigned short*)(ws + 2113536);   // 4480 B (8 KiB slot)
  unsigned short* x1m = (unsigned short*)(ws + 2121728);             // 64 MiB
  unsigned short* x2m = (unsigned short*)(ws + 2121728 + 67108864);  // 64 MiB

  float* out = (float*)d_out;
  // scratch in d_out (all dead before kF writes out):
  float* xh_ws = (float*)d_out;                             // 1 MiB
  float* xw_ws = (float*)d_out + 262144;                    // 1 MiB
  float* sighA = (float*)((char*)d_out + 2097152);          // 1 MiB
  float* Bgn   = (float*)((char*)d_out + 3145728);          // 8 KiB
  float* gacc  = (float*)((char*)d_out + 3153920);          // 32 KiB

  hipMemsetAsync(gacc, 0, NN*32*sizeof(float), stream);
  kWB<<<23, 256, 0, stream>>>(w1, w3, w5, scw, spw, BHg, BLog);
  kA1<<<NN*CG, 256, 0, stream>>>(x, xh_ws, xw_ws);
  kA2<<<NN, 256, 0, stream>>>(xh_ws, xw_ws, afw, sig_h, sig_w);
  kB <<<NN*CG, 256, 0, stream>>>(x, sig_h, sig_w, gnw, gnb, Bgn, sighA);
  kC <<<NN*16, 256, 0, stream>>>(x, w1, scw, spw, sig_w, sighA, Bgn, BHg, BLog, x1m, x2m, gacc);
  kT <<<4, 64, 0, stream>>>(gacc, cgw, a1a2);
  kF <<<NN*16, 256, 0, stream>>>(x, x1m, x2m, a1a2, spw, out);
}